// Round 18
// baseline (206.167 us; speedup 1.0000x reference)
//
#include <hip/hip_runtime.h>
#include <hip/hip_cooperative_groups.h>
#include <cstddef>

namespace cg = cooperative_groups;

#define NPTS   2048
#define NB     16
#define MROWS  (NPTS*NB)   // 32768
#define BN_EPS 1e-5f

typedef __attribute__((ext_vector_type(8))) short bf16x8;
typedef __attribute__((ext_vector_type(4))) float f32x4;
typedef __attribute__((ext_vector_type(2))) float f32x2;

// HW packed convert: dst = {lo16: bf16(a), hi16: bf16(b)} — 1 VALU instr
__device__ inline unsigned cvtpk(float a, float b) {
    unsigned r;
    asm("v_cvt_pk_bf16_f32 %0, %1, %2" : "=v"(r) : "v"(a), "v"(b));
    return r;
}
// same but with |.| input modifiers (free on VOP3)
__device__ inline unsigned cvtpk_abs(float a, float b) {
    unsigned r;
    asm("v_cvt_pk_bf16_f32 %0, |%1|, |%2|" : "=v"(r) : "v"(a), "v"(b));
    return r;
}

union U4 { unsigned u[4]; bf16x8 v; };

// ---------------------------------------------------------------------------
// prep_k: fused weight-pack + xyz transpose (r14-validated).
// ---------------------------------------------------------------------------
__global__ __launch_bounds__(256) void prep_k(
    const float* __restrict__ Wf, const float* __restrict__ Wb,
    const float* __restrict__ Wag, const float* __restrict__ xyz,
    unsigned short* __restrict__ Wpk, unsigned short* __restrict__ Wpk2,
    float* __restrict__ xT)
{
    const int bid = blockIdx.x;
    if (bid < 8) {
        const int gid  = bid*256 + threadIdx.x;   // 0..2047
        const int lane = gid & 63;
        const int n    = ((gid >> 7) << 4) + (lane & 15);
        const int k0   = (((gid >> 6) & 1) << 5) + ((lane >> 4) << 3);
        unsigned o[4];
        #pragma unroll
        for (int p = 0; p < 4; ++p) {
            const int ka = k0 + 2*p, kb = ka + 1;
            const float va = (n < 64) ? Wf[ka*64 + n] : Wb[ka*192 + (n - 64)];
            const float vb = (n < 64) ? Wf[kb*64 + n] : Wb[kb*192 + (n - 64)];
            o[p] = cvtpk(va, vb);
        }
        uint4 ov = { o[0], o[1], o[2], o[3] };
        *(uint4*)(Wpk + (size_t)gid * 8) = ov;
    } else if (bid == 8) {
        const int g2   = threadIdx.x;     // 0..255
        const int lane = g2 & 63;
        const int nt   = g2 >> 6;
        const int n    = nt*16 + (lane & 15);
        const int k0   = (lane >> 4) * 8;
        unsigned o[4];
        #pragma unroll
        for (int p = 0; p < 4; ++p) {
            const int ka = k0 + 2*p, kb = ka + 1;
            o[p] = cvtpk(Wag[ka*64 + n], Wag[kb*64 + n]);
        }
        uint4 ov = { o[0], o[1], o[2], o[3] };
        *(uint4*)(Wpk2 + (size_t)g2 * 8) = ov;
    } else {
        const int t = (bid - 9) * 256 + threadIdx.x;
        if (t < NB*NPTS) {
            const int b = t >> 11, j = t & (NPTS-1);
            const float* p = xyz + (size_t)t * 3;
            xT[((size_t)b*3 + 0)*NPTS + j] = p[0];
            xT[((size_t)b*3 + 1)*NPTS + j] = p[1];
            xT[((size_t)b*3 + 2)*NPTS + j] = p[2];
        }
    }
}

// ---------------------------------------------------------------------------
// linear1 v5 (MFMA, epilogue atomics) — r14-validated.
// ---------------------------------------------------------------------------
__global__ __launch_bounds__(256) void linear1_mfma_k(
    const float* __restrict__ feat, const unsigned short* __restrict__ Wpk,
    const float* __restrict__ bf,
    float* __restrict__ selfF, float* __restrict__ preB,
    float* __restrict__ s192s, float* __restrict__ s192q)
{
    __shared__ float lps[4][12][16];
    __shared__ float lpq[4][12][16];
    const int t    = threadIdx.x;
    const int lane = t & 63;
    const int w    = t >> 6;
    const int r0   = blockIdx.x * 64 + w * 16;
    const int mrow = lane & 15;
    const int kgrp = lane >> 4;

    U4 Afr[2];
    #pragma unroll
    for (int ks = 0; ks < 2; ++ks) {
        const float* src = feat + (size_t)(r0 + mrow)*64 + ks*32 + kgrp*8;
        const float4 v0 = *(const float4*)src;
        const float4 v1 = *(const float4*)(src + 4);
        Afr[ks].u[0] = cvtpk(v0.x, v0.y);
        Afr[ks].u[1] = cvtpk(v0.z, v0.w);
        Afr[ks].u[2] = cvtpk(v1.x, v1.y);
        Afr[ks].u[3] = cvtpk(v1.z, v1.w);
    }

    #pragma unroll 4
    for (int nt = 0; nt < 16; ++nt) {
        const unsigned short* wp = Wpk + (size_t)(nt*2)*512 + lane*8;
        const bf16x8 B0 = *(const bf16x8*)(wp);
        const bf16x8 B1 = *(const bf16x8*)(wp + 512);
        f32x4 acc = {0.f, 0.f, 0.f, 0.f};
        acc = __builtin_amdgcn_mfma_f32_16x16x32_bf16(Afr[0].v, B0, acc, 0,0,0);
        acc = __builtin_amdgcn_mfma_f32_16x16x32_bf16(Afr[1].v, B1, acc, 0,0,0);

        const int ncol = nt*16 + mrow;
        if (nt < 4) {
            const float bias = bf[ncol];
            #pragma unroll
            for (int r = 0; r < 4; ++r)
                selfF[(size_t)(r0 + kgrp*4 + r)*64 + ncol] = acc[r] + bias;
        } else {
            float s = 0.f, q = 0.f;
            #pragma unroll
            for (int r = 0; r < 4; ++r) {
                const float v = acc[r];
                preB[(size_t)(r0 + kgrp*4 + r)*192 + (ncol - 64)] = v;
                s += v; q = fmaf(v, v, q);
            }
            s += __shfl_xor(s, 16);  s += __shfl_xor(s, 32);
            q += __shfl_xor(q, 16);  q += __shfl_xor(q, 32);
            if (lane < 16) {
                lps[w][nt-4][lane] = s;
                lpq[w][nt-4][lane] = q;
            }
        }
    }
    __syncthreads();
    if (t < 192) {
        const int ni = t >> 4, la = t & 15;
        const float s = lps[0][ni][la] + lps[1][ni][la] + lps[2][ni][la] + lps[3][ni][la];
        const float q = lpq[0][ni][la] + lpq[1][ni][la] + lpq[2][ni][la] + lpq[3][ni][la];
        atomicAdd(s192s + t, s);
        atomicAdd(s192q + t, q);
    }
}

// ---------------------------------------------------------------------------
// BN+relu of pre_byp -> pre-packed bf16 DIFF/SUM B-fragments (r14-validated).
// ---------------------------------------------------------------------------
__global__ __launch_bounds__(256) void bn_t192_k(
    const float* __restrict__ sum, const float* __restrict__ sq,
    const float* __restrict__ g,   const float* __restrict__ be,
    const float* __restrict__ X,   unsigned short* __restrict__ mTf)
{
    __shared__ float ltile[64][65];
    const int bid = blockIdx.x;
    const int ax  = bid % 3;
    const int jb  = (bid / 3) % 32;
    const int b   = bid / 96;
    const int t   = threadIdx.x;

    const int cl = t & 63;
    const int c  = ax*64 + cl;
    const float invM = 1.0f / (float)MROWS;
    const float mu  = sum[c] * invM;
    const float var = sq[c] * invM - mu*mu;
    const float sc  = g[c] * rsqrtf(var + BN_EPS);
    const float sh  = be[c] - mu * sc;

    const float* __restrict__ Xb = X + ((size_t)b*NPTS + jb*64) * 192;
    #pragma unroll
    for (int rr = 0; rr < 16; ++rr) {
        const int j = (t >> 6) + rr*4;
        const float v = Xb[(size_t)j*192 + c];
        ltile[cl][j] = fmaxf(fmaf(v, sc, sh), 0.0f);
    }
    __syncthreads();

    const int lane = t & 63;
    const int h    = (t >> 6) & 1;
    const int sd   = (t >> 7) & 1;
    const int cc   = h*16 + (lane & 15);
    const int jB   = (lane >> 4) * 8;
    const float sgn = sd ? 0.5f : -0.5f;
    #pragma unroll
    for (int js = 0; js < 2; ++js) {
        unsigned o[4];
        #pragma unroll
        for (int p = 0; p < 4; ++p) {
            const int j = js*32 + jB + 2*p;
            const float vlo = fmaf(ltile[cc+32][j],   sgn, ltile[cc][j]   * 0.5f);
            const float vhi = fmaf(ltile[cc+32][j+1], sgn, ltile[cc][j+1] * 0.5f);
            o[p] = cvtpk(vlo, vhi);
        }
        const int slot = ax*2 + sd;
        unsigned short* dst = mTf + ((((size_t)(b*64 + jb*2 + js)*6 + slot)*2 + h)*64 + lane)*8;
        uint4 ov = { o[0], o[1], o[2], o[3] };
        *(uint4*)dst = ov;
    }
}

// ---------------------------------------------------------------------------
// MFMA aggregate v9 (r17-validated): plain-C f32x2 weight math.
// ---------------------------------------------------------------------------
__global__ __launch_bounds__(256) void aggregate_mfma_k(
    const unsigned short* __restrict__ mTf,
    const float* __restrict__ xT,
    float* __restrict__ agp,          // [2][MROWS][32]
    float* __restrict__ nrmp)         // [2][MROWS]
{
    __shared__ float lacc[4][32][32];
    __shared__ float lnorm[4][32];

    const int bid = blockIdx.x;
    const int swz = (bid & 7) * 256 + (bid >> 3);   // bijective for 2048
    const int b     = swz >> 7;
    const int rem   = swz & 127;
    const int i0    = (rem >> 1) << 5;
    const int jhalf = rem & 1;
    const int t    = threadIdx.x;
    const int lane = t & 63;
    const int w    = t >> 6;
    const int iloc = lane & 15;
    const int kgrp = lane >> 4;

    const float* __restrict__ xb = xT + (size_t)b * 3 * NPTS;
    const unsigned short* __restrict__ mb = mTf + (size_t)b * 64 * 12 * 512;

    const float xi0 = xb[0*NPTS + i0 + iloc],      yi0 = xb[1*NPTS + i0 + iloc],      zi0 = xb[2*NPTS + i0 + iloc];
    const float xi1 = xb[0*NPTS + i0 + 16 + iloc], yi1 = xb[1*NPTS + i0 + 16 + iloc], zi1 = xb[2*NPTS + i0 + 16 + iloc];

    f32x4 acc[2][2];
    #pragma unroll
    for (int a = 0; a < 2; ++a)
        #pragma unroll
        for (int h = 0; h < 2; ++h) acc[a][h] = f32x4{0.f,0.f,0.f,0.f};
    float nrm0 = 0.0f, nrm1 = 0.0f;

    const float dr2   = 0.30f*0.30f;
    const float invdr = 1.0f / (dr2 - 0.15f*0.15f);
    const float drc   = dr2 * invdr;
    const f32x2 mind2 = {-invdr, -invdr};
    const f32x2 drc2  = {drc, drc};

    const int jbase = jhalf*1024 + w*256;
    for (int j0 = jbase; j0 < jbase + 256; j0 += 32) {
        const int jj = j0 + kgrp*8;
        const float4 a0 = *(const float4*)(xb + 0*NPTS + jj);
        const float4 a1 = *(const float4*)(xb + 0*NPTS + jj + 4);
        const float4 b0 = *(const float4*)(xb + 1*NPTS + jj);
        const float4 b1 = *(const float4*)(xb + 1*NPTS + jj + 4);
        const float4 c0 = *(const float4*)(xb + 2*NPTS + jj);
        const float4 c1 = *(const float4*)(xb + 2*NPTS + jj + 4);
        const f32x2 px[4] = {{a0.x,a0.y},{a0.z,a0.w},{a1.x,a1.y},{a1.z,a1.w}};
        const f32x2 py[4] = {{b0.x,b0.y},{b0.z,b0.w},{b1.x,b1.y},{b1.z,b1.w}};
        const f32x2 pz[4] = {{c0.x,c0.y},{c0.z,c0.w},{c1.x,c1.y},{c1.z,c1.w}};

        U4 pwS[2][3], pwA[2][3];
        #pragma unroll
        for (int it = 0; it < 2; ++it) {
            const float xi = it ? xi1 : xi0;
            const float yi = it ? yi1 : yi0;
            const float zi = it ? zi1 : zi0;
            const f32x2 xi2 = {xi, xi};
            const f32x2 yi2 = {yi, yi};
            const f32x2 zi2 = {zi, zi};
            #pragma unroll
            for (int p = 0; p < 4; ++p) {
                const f32x2 dx = px[p] - xi2;
                const f32x2 dy = py[p] - yi2;
                const f32x2 dz = pz[p] - zi2;
                const f32x2 d2 = dx*dx + dy*dy + dz*dz;
                const f32x2 wdl = d2*mind2 + drc2;
                const float wd0 = __builtin_amdgcn_fmed3f(wdl.x, 0.0f, 1.0f);
                const float wd1 = __builtin_amdgcn_fmed3f(wdl.y, 0.0f, 1.0f);
                if (it) { nrm1 += wd0; nrm1 += wd1; }
                else    { nrm0 += wd0; nrm0 += wd1; }
                const f32x2 inv2 = { wd0 * __builtin_amdgcn_rcpf(fmaxf(d2.x, 1e-12f)),
                                     wd1 * __builtin_amdgcn_rcpf(fmaxf(d2.y, 1e-12f)) };
                #pragma unroll
                for (int ax = 0; ax < 3; ++ax) {
                    const f32x2 da = (ax == 0) ? dx : (ax == 1) ? dy : dz;
                    const f32x2 u = da * inv2;
                    const float s0 = u.x * __builtin_fabsf(da.x);
                    const float s1 = u.y * __builtin_fabsf(da.y);
                    pwS[it][ax].u[p] = cvtpk(s0, s1);
                    pwA[it][ax].u[p] = cvtpk_abs(s0, s1);
                }
            }
        }

        const unsigned short* sb = mb + (size_t)(j0 >> 5) * 12 * 512 + lane*8;
        #pragma unroll
        for (int ax = 0; ax < 3; ++ax) {
            #pragma unroll
            for (int h = 0; h < 2; ++h) {
                const bf16x8 Bd = *(const bf16x8*)(sb + (size_t)((2*ax  )*2 + h)*512);
                const bf16x8 Bs = *(const bf16x8*)(sb + (size_t)((2*ax+1)*2 + h)*512);
                acc[0][h] = __builtin_amdgcn_mfma_f32_16x16x32_bf16(pwS[0][ax].v, Bd, acc[0][h], 0,0,0);
                acc[0][h] = __builtin_amdgcn_mfma_f32_16x16x32_bf16(pwA[0][ax].v, Bs, acc[0][h], 0,0,0);
                acc[1][h] = __builtin_amdgcn_mfma_f32_16x16x32_bf16(pwS[1][ax].v, Bd, acc[1][h], 0,0,0);
                acc[1][h] = __builtin_amdgcn_mfma_f32_16x16x32_bf16(pwA[1][ax].v, Bs, acc[1][h], 0,0,0);
            }
        }
    }

    nrm0 += __shfl_xor(nrm0, 16);  nrm0 += __shfl_xor(nrm0, 32);
    nrm1 += __shfl_xor(nrm1, 16);  nrm1 += __shfl_xor(nrm1, 32);

    #pragma unroll
    for (int it = 0; it < 2; ++it)
        #pragma unroll
        for (int r = 0; r < 4; ++r) {
            lacc[w][it*16 + kgrp*4 + r][iloc]      = acc[it][0][r];
            lacc[w][it*16 + kgrp*4 + r][16 + iloc] = acc[it][1][r];
        }
    if (lane < 16) { lnorm[w][lane] = nrm0; lnorm[w][16 + lane] = nrm1; }
    __syncthreads();

    float* agh = agp + (size_t)jhalf * MROWS * 32;
    #pragma unroll
    for (int rep = 0; rep < 4; ++rep) {
        const int idx = t + rep*256;
        const int i = idx >> 5, c = idx & 31;
        const float s = lacc[0][i][c] + lacc[1][i][c] + lacc[2][i][c] + lacc[3][i][c];
        agh[((size_t)b*NPTS + i0 + i)*32 + c] = s;
    }
    if (t < 32) {
        const float n = lnorm[0][t] + lnorm[1][t] + lnorm[2][t] + lnorm[3][t];
        nrmp[(size_t)jhalf*MROWS + b*NPTS + i0 + t] = n;
    }
}

// ---------------------------------------------------------------------------
// tail_k (COOPERATIVE, 512 blocks): finalize + bn1relu + lin2 + bn2relu.
// Each block owns rows r0..r0+63 across all phases; row data lives in LDS,
// so ag and pre2 never touch global memory. grid.sync() at the two BN-stats
// barriers (device-scope visibility of the epilogue atomics).
// ---------------------------------------------------------------------------
__global__ __launch_bounds__(256) void tail_k(
    const float* __restrict__ agp, const float* __restrict__ nrmp,
    float* __restrict__ s32s, float* __restrict__ s32q,
    const float* __restrict__ g1,  const float* __restrict__ be1,
    const unsigned short* __restrict__ Wpk2,
    const float* __restrict__ bag, const float* __restrict__ selfF,
    float* __restrict__ s64s, float* __restrict__ s64q,
    const float* __restrict__ g2,  const float* __restrict__ be2,
    float* __restrict__ out)
{
    cg::grid_group grid = cg::this_grid();
    __shared__ float lv[64][33];       // ag rows (phase 1 -> 2)
    __shared__ float pre2l[64][65];    // pre2 rows (phase 2 -> 3), padded
    __shared__ float sc_[64], sh_[64];
    __shared__ float lps[4][4][16], lpq[4][4][16];

    const int t  = threadIdx.x;
    const int r0 = blockIdx.x * 64;
    const int lane = t & 63;
    const int w    = t >> 6;
    const int mrow = lane & 15;
    const int kgrp = lane >> 4;

    // ---- Phase 1: merge j-half partials, normalize, s32 stats (r17 body) ----
    #pragma unroll
    for (int rep = 0; rep < 2; ++rep) {
        const int lidx = t + rep*256;
        const int rl = lidx >> 3;
        const int c0 = (lidx & 7) * 4;
        const size_t r = (size_t)r0 + rl;
        const float4 p0 = *(const float4*)(agp + r*32 + c0);
        const float4 p1 = *(const float4*)(agp + ((size_t)MROWS + r)*32 + c0);
        const float n = nrmp[r] + nrmp[MROWS + r] - 1.0f;
        const float invn = __builtin_amdgcn_rcpf(fmaxf(n, 1e-12f));
        lv[rl][c0]   = (p0.x + p1.x) * invn;
        lv[rl][c0+1] = (p0.y + p1.y) * invn;
        lv[rl][c0+2] = (p0.z + p1.z) * invn;
        lv[rl][c0+3] = (p0.w + p1.w) * invn;
    }
    __syncthreads();
    if (t < 32) {
        float ps = 0.0f, pq = 0.0f;
        #pragma unroll
        for (int i = 0; i < 64; ++i) {
            const float v = lv[i][t];
            ps += v; pq = fmaf(v, v, pq);
        }
        atomicAdd(s32s + t, ps);
        atomicAdd(s32q + t, pq);
    }
    grid.sync();

    // ---- Phase 2: bn1relu(LDS) @ Wag + bag + selfF -> pre2l; s64 stats ----
    if (t < 32) {
        const float invM = 1.0f / (float)MROWS;
        const float mu  = s32s[t] * invM;
        const float var = s32q[t] * invM - mu*mu;
        const float sc  = g1[t] * rsqrtf(var + BN_EPS);
        sc_[t] = sc; sh_[t] = be1[t] - mu * sc;
    }
    __syncthreads();

    U4 Afr;
    {
        const int rl = w*16 + mrow;
        const int c0 = kgrp*8;
        float bn[8];
        #pragma unroll
        for (int e = 0; e < 8; ++e)
            bn[e] = fmaxf(fmaf(lv[rl][c0+e], sc_[c0+e], sh_[c0+e]), 0.0f);
        Afr.u[0] = cvtpk(bn[0], bn[1]);
        Afr.u[1] = cvtpk(bn[2], bn[3]);
        Afr.u[2] = cvtpk(bn[4], bn[5]);
        Afr.u[3] = cvtpk(bn[6], bn[7]);
    }

    #pragma unroll
    for (int nt = 0; nt < 4; ++nt) {
        const bf16x8 B = *(const bf16x8*)(Wpk2 + (size_t)nt*512 + lane*8);
        f32x4 acc = {0.f,0.f,0.f,0.f};
        acc = __builtin_amdgcn_mfma_f32_16x16x32_bf16(Afr.v, B, acc, 0,0,0);

        const int ncol = nt*16 + mrow;
        const float bias = bag[ncol];
        float s = 0.f, q = 0.f;
        #pragma unroll
        for (int r = 0; r < 4; ++r) {
            const int rl = w*16 + kgrp*4 + r;
            const float val = acc[r] + bias + selfF[(size_t)(r0 + rl)*64 + ncol];
            pre2l[rl][ncol] = val;
            s += val; q = fmaf(val, val, q);
        }
        s += __shfl_xor(s, 16);  s += __shfl_xor(s, 32);
        q += __shfl_xor(q, 16);  q += __shfl_xor(q, 32);
        if (lane < 16) { lps[w][nt][lane] = s; lpq[w][nt][lane] = q; }
    }
    __syncthreads();
    if (t < 64) {
        const int nt = t >> 4, la = t & 15;
        const float s = lps[0][nt][la] + lps[1][nt][la] + lps[2][nt][la] + lps[3][nt][la];
        const float q = lpq[0][nt][la] + lpq[1][nt][la] + lpq[2][nt][la] + lpq[3][nt][la];
        atomicAdd(s64s + t, s);
        atomicAdd(s64q + t, q);
    }
    grid.sync();

    // ---- Phase 3: bn2 + relu from pre2l -> out ----
    if (t < 64) {
        const float invM = 1.0f / (float)MROWS;
        const float mu  = s64s[t] * invM;
        const float var = s64q[t] * invM - mu*mu;
        const float sc  = g2[t] * rsqrtf(var + BN_EPS);
        sc_[t] = sc; sh_[t] = be2[t] - mu * sc;
    }
    __syncthreads();
    #pragma unroll
    for (int rep = 0; rep < 4; ++rep) {
        const int lidx = t + rep*256;
        const int row = lidx >> 4;
        const int c0  = (lidx & 15) * 4;
        float4 v;
        v.x = fmaxf(fmaf(pre2l[row][c0+0], sc_[c0+0], sh_[c0+0]), 0.0f);
        v.y = fmaxf(fmaf(pre2l[row][c0+1], sc_[c0+1], sh_[c0+1]), 0.0f);
        v.z = fmaxf(fmaf(pre2l[row][c0+2], sc_[c0+2], sh_[c0+2]), 0.0f);
        v.w = fmaxf(fmaf(pre2l[row][c0+3], sc_[c0+3], sh_[c0+3]), 0.0f);
        *(float4*)(out + (size_t)(r0 + row)*64 + c0) = v;
    }
}

// ---------------------------------------------------------------------------
extern "C" void kernel_launch(void* const* d_in, const int* in_sizes, int n_in,
                              void* d_out, int out_size, void* d_ws, size_t ws_size,
                              hipStream_t stream)
{
    const float* feat = (const float*)d_in[0];
    const float* xyz  = (const float*)d_in[1];
    const float* Wf   = (const float*)d_in[2];
    const float* bf   = (const float*)d_in[3];
    const float* Wb   = (const float*)d_in[4];
    const float* gby  = (const float*)d_in[5];
    const float* beby = (const float*)d_in[6];
    const float* g1   = (const float*)d_in[7];
    const float* be1  = (const float*)d_in[8];
    const float* Wag  = (const float*)d_in[9];
    const float* bag  = (const float*)d_in[10];
    const float* g2   = (const float*)d_in[11];
    const float* be2  = (const float*)d_in[12];

    float* ws = (float*)d_ws;
    float* stats = ws;                                  // 1024 f
    float* A   = ws + 1024;                             // self_feat [32768][64]
    float* B   = A + (size_t)MROWS*64;                  // preB; later agp/nrmp
    float* C   = B + (size_t)MROWS*192;                 // (unused now)
    float* xT  = C + (size_t)MROWS*32;                  // [16][3][2048]
    unsigned short* mTf  = (unsigned short*)(xT + (size_t)NB*3*NPTS);
    unsigned short* Wpk  = mTf + (size_t)NB*64*12*512;  // 16384 shorts
    unsigned short* Wpk2 = Wpk + 16384;                 // 2048 shorts
    float* agp  = B;                                    // [2][MROWS][32]
    float* nrmp = B + (size_t)MROWS*64;                 // [2][MROWS]

    float* s192s = stats;       float* s192q = stats + 192;
    float* s32s  = stats + 384; float* s32q  = stats + 416;
    float* s64s  = stats + 448; float* s64q  = stats + 512;

    (void)hipMemsetAsync(stats, 0, 1024 * sizeof(float), stream);

    prep_k<<<137, 256, 0, stream>>>(Wf, Wb, Wag, xyz, Wpk, Wpk2, xT);
    linear1_mfma_k<<<512, 256, 0, stream>>>(feat, Wpk, bf, A, B, s192s, s192q);

    bn_t192_k<<<1536, 256, 0, stream>>>(s192s, s192q, gby, beby, B, mTf);

    aggregate_mfma_k<<<2048, 256, 0, stream>>>(mTf, xT, agp, nrmp);

    float* outp = (float*)d_out;
    void* args[] = {
        (void*)&agp, (void*)&nrmp,
        (void*)&s32s, (void*)&s32q,
        (void*)&g1, (void*)&be1,
        (void*)&Wpk2, (void*)&bag, (void*)&A,
        (void*)&s64s, (void*)&s64q,
        (void*)&g2, (void*)&be2,
        (void*)&outp
    };
    (void)hipLaunchCooperativeKernel((void*)tail_k, dim3(512), dim3(256),
                                     args, 0, stream);
}

// Round 19
// 131.528 us; speedup vs baseline: 1.5675x; 1.5675x over previous
//
#include <hip/hip_runtime.h>
#include <cstddef>

#define NPTS   2048
#define NB     16
#define MROWS  (NPTS*NB)   // 32768
#define BN_EPS 1e-5f

typedef __attribute__((ext_vector_type(8))) short bf16x8;
typedef __attribute__((ext_vector_type(4))) float f32x4;
typedef __attribute__((ext_vector_type(2))) float f32x2;

// HW packed convert: dst = {lo16: bf16(a), hi16: bf16(b)} — 1 VALU instr
__device__ inline unsigned cvtpk(float a, float b) {
    unsigned r;
    asm("v_cvt_pk_bf16_f32 %0, %1, %2" : "=v"(r) : "v"(a), "v"(b));
    return r;
}
// same but with |.| input modifiers (free on VOP3)
__device__ inline unsigned cvtpk_abs(float a, float b) {
    unsigned r;
    asm("v_cvt_pk_bf16_f32 %0, |%1|, |%2|" : "=v"(r) : "v"(a), "v"(b));
    return r;
}

union U4 { unsigned u[4]; bf16x8 v; };

// ---------------------------------------------------------------------------
// prep_k: fused weight-pack + xyz transpose (r14-validated).
// ---------------------------------------------------------------------------
__global__ __launch_bounds__(256) void prep_k(
    const float* __restrict__ Wf, const float* __restrict__ Wb,
    const float* __restrict__ Wag, const float* __restrict__ xyz,
    unsigned short* __restrict__ Wpk, unsigned short* __restrict__ Wpk2,
    float* __restrict__ xT)
{
    const int bid = blockIdx.x;
    if (bid < 8) {
        const int gid  = bid*256 + threadIdx.x;   // 0..2047
        const int lane = gid & 63;
        const int n    = ((gid >> 7) << 4) + (lane & 15);
        const int k0   = (((gid >> 6) & 1) << 5) + ((lane >> 4) << 3);
        unsigned o[4];
        #pragma unroll
        for (int p = 0; p < 4; ++p) {
            const int ka = k0 + 2*p, kb = ka + 1;
            const float va = (n < 64) ? Wf[ka*64 + n] : Wb[ka*192 + (n - 64)];
            const float vb = (n < 64) ? Wf[kb*64 + n] : Wb[kb*192 + (n - 64)];
            o[p] = cvtpk(va, vb);
        }
        uint4 ov = { o[0], o[1], o[2], o[3] };
        *(uint4*)(Wpk + (size_t)gid * 8) = ov;
    } else if (bid == 8) {
        const int g2   = threadIdx.x;     // 0..255
        const int lane = g2 & 63;
        const int nt   = g2 >> 6;
        const int n    = nt*16 + (lane & 15);
        const int k0   = (lane >> 4) * 8;
        unsigned o[4];
        #pragma unroll
        for (int p = 0; p < 4; ++p) {
            const int ka = k0 + 2*p, kb = ka + 1;
            o[p] = cvtpk(Wag[ka*64 + n], Wag[kb*64 + n]);
        }
        uint4 ov = { o[0], o[1], o[2], o[3] };
        *(uint4*)(Wpk2 + (size_t)g2 * 8) = ov;
    } else {
        const int t = (bid - 9) * 256 + threadIdx.x;
        if (t < NB*NPTS) {
            const int b = t >> 11, j = t & (NPTS-1);
            const float* p = xyz + (size_t)t * 3;
            xT[((size_t)b*3 + 0)*NPTS + j] = p[0];
            xT[((size_t)b*3 + 1)*NPTS + j] = p[1];
            xT[((size_t)b*3 + 2)*NPTS + j] = p[2];
        }
    }
}

// ---------------------------------------------------------------------------
// linear1 v5 (MFMA, epilogue atomics) — r14-validated.
// ---------------------------------------------------------------------------
__global__ __launch_bounds__(256) void linear1_mfma_k(
    const float* __restrict__ feat, const unsigned short* __restrict__ Wpk,
    const float* __restrict__ bf,
    float* __restrict__ selfF, float* __restrict__ preB,
    float* __restrict__ s192s, float* __restrict__ s192q)
{
    __shared__ float lps[4][12][16];
    __shared__ float lpq[4][12][16];
    const int t    = threadIdx.x;
    const int lane = t & 63;
    const int w    = t >> 6;
    const int r0   = blockIdx.x * 64 + w * 16;
    const int mrow = lane & 15;
    const int kgrp = lane >> 4;

    U4 Afr[2];
    #pragma unroll
    for (int ks = 0; ks < 2; ++ks) {
        const float* src = feat + (size_t)(r0 + mrow)*64 + ks*32 + kgrp*8;
        const float4 v0 = *(const float4*)src;
        const float4 v1 = *(const float4*)(src + 4);
        Afr[ks].u[0] = cvtpk(v0.x, v0.y);
        Afr[ks].u[1] = cvtpk(v0.z, v0.w);
        Afr[ks].u[2] = cvtpk(v1.x, v1.y);
        Afr[ks].u[3] = cvtpk(v1.z, v1.w);
    }

    #pragma unroll 4
    for (int nt = 0; nt < 16; ++nt) {
        const unsigned short* wp = Wpk + (size_t)(nt*2)*512 + lane*8;
        const bf16x8 B0 = *(const bf16x8*)(wp);
        const bf16x8 B1 = *(const bf16x8*)(wp + 512);
        f32x4 acc = {0.f, 0.f, 0.f, 0.f};
        acc = __builtin_amdgcn_mfma_f32_16x16x32_bf16(Afr[0].v, B0, acc, 0,0,0);
        acc = __builtin_amdgcn_mfma_f32_16x16x32_bf16(Afr[1].v, B1, acc, 0,0,0);

        const int ncol = nt*16 + mrow;
        if (nt < 4) {
            const float bias = bf[ncol];
            #pragma unroll
            for (int r = 0; r < 4; ++r)
                selfF[(size_t)(r0 + kgrp*4 + r)*64 + ncol] = acc[r] + bias;
        } else {
            float s = 0.f, q = 0.f;
            #pragma unroll
            for (int r = 0; r < 4; ++r) {
                const float v = acc[r];
                preB[(size_t)(r0 + kgrp*4 + r)*192 + (ncol - 64)] = v;
                s += v; q = fmaf(v, v, q);
            }
            s += __shfl_xor(s, 16);  s += __shfl_xor(s, 32);
            q += __shfl_xor(q, 16);  q += __shfl_xor(q, 32);
            if (lane < 16) {
                lps[w][nt-4][lane] = s;
                lpq[w][nt-4][lane] = q;
            }
        }
    }
    __syncthreads();
    if (t < 192) {
        const int ni = t >> 4, la = t & 15;
        const float s = lps[0][ni][la] + lps[1][ni][la] + lps[2][ni][la] + lps[3][ni][la];
        const float q = lpq[0][ni][la] + lpq[1][ni][la] + lpq[2][ni][la] + lpq[3][ni][la];
        atomicAdd(s192s + t, s);
        atomicAdd(s192q + t, q);
    }
}

// ---------------------------------------------------------------------------
// BN+relu of pre_byp -> pre-packed bf16 DIFF/SUM B-fragments (r14-validated).
// ---------------------------------------------------------------------------
__global__ __launch_bounds__(256) void bn_t192_k(
    const float* __restrict__ sum, const float* __restrict__ sq,
    const float* __restrict__ g,   const float* __restrict__ be,
    const float* __restrict__ X,   unsigned short* __restrict__ mTf)
{
    __shared__ float ltile[64][65];
    const int bid = blockIdx.x;
    const int ax  = bid % 3;
    const int jb  = (bid / 3) % 32;
    const int b   = bid / 96;
    const int t   = threadIdx.x;

    const int cl = t & 63;
    const int c  = ax*64 + cl;
    const float invM = 1.0f / (float)MROWS;
    const float mu  = sum[c] * invM;
    const float var = sq[c] * invM - mu*mu;
    const float sc  = g[c] * rsqrtf(var + BN_EPS);
    const float sh  = be[c] - mu * sc;

    const float* __restrict__ Xb = X + ((size_t)b*NPTS + jb*64) * 192;
    #pragma unroll
    for (int rr = 0; rr < 16; ++rr) {
        const int j = (t >> 6) + rr*4;
        const float v = Xb[(size_t)j*192 + c];
        ltile[cl][j] = fmaxf(fmaf(v, sc, sh), 0.0f);
    }
    __syncthreads();

    const int lane = t & 63;
    const int h    = (t >> 6) & 1;
    const int sd   = (t >> 7) & 1;
    const int cc   = h*16 + (lane & 15);
    const int jB   = (lane >> 4) * 8;
    const float sgn = sd ? 0.5f : -0.5f;
    #pragma unroll
    for (int js = 0; js < 2; ++js) {
        unsigned o[4];
        #pragma unroll
        for (int p = 0; p < 4; ++p) {
            const int j = js*32 + jB + 2*p;
            const float vlo = fmaf(ltile[cc+32][j],   sgn, ltile[cc][j]   * 0.5f);
            const float vhi = fmaf(ltile[cc+32][j+1], sgn, ltile[cc][j+1] * 0.5f);
            o[p] = cvtpk(vlo, vhi);
        }
        const int slot = ax*2 + sd;
        unsigned short* dst = mTf + ((((size_t)(b*64 + jb*2 + js)*6 + slot)*2 + h)*64 + lane)*8;
        uint4 ov = { o[0], o[1], o[2], o[3] };
        *(uint4*)dst = ov;
    }
}

// ---------------------------------------------------------------------------
// MFMA aggregate v9 (r17-validated): plain-C f32x2 weight math.
// ---------------------------------------------------------------------------
__global__ __launch_bounds__(256) void aggregate_mfma_k(
    const unsigned short* __restrict__ mTf,
    const float* __restrict__ xT,
    float* __restrict__ agp,          // [2][MROWS][32]
    float* __restrict__ nrmp)         // [2][MROWS]
{
    __shared__ float lacc[4][32][32];
    __shared__ float lnorm[4][32];

    const int bid = blockIdx.x;
    const int swz = (bid & 7) * 256 + (bid >> 3);   // bijective for 2048
    const int b     = swz >> 7;
    const int rem   = swz & 127;
    const int i0    = (rem >> 1) << 5;
    const int jhalf = rem & 1;
    const int t    = threadIdx.x;
    const int lane = t & 63;
    const int w    = t >> 6;
    const int iloc = lane & 15;
    const int kgrp = lane >> 4;

    const float* __restrict__ xb = xT + (size_t)b * 3 * NPTS;
    const unsigned short* __restrict__ mb = mTf + (size_t)b * 64 * 12 * 512;

    const float xi0 = xb[0*NPTS + i0 + iloc],      yi0 = xb[1*NPTS + i0 + iloc],      zi0 = xb[2*NPTS + i0 + iloc];
    const float xi1 = xb[0*NPTS + i0 + 16 + iloc], yi1 = xb[1*NPTS + i0 + 16 + iloc], zi1 = xb[2*NPTS + i0 + 16 + iloc];

    f32x4 acc[2][2];
    #pragma unroll
    for (int a = 0; a < 2; ++a)
        #pragma unroll
        for (int h = 0; h < 2; ++h) acc[a][h] = f32x4{0.f,0.f,0.f,0.f};
    float nrm0 = 0.0f, nrm1 = 0.0f;

    const float dr2   = 0.30f*0.30f;
    const float invdr = 1.0f / (dr2 - 0.15f*0.15f);
    const float drc   = dr2 * invdr;
    const f32x2 mind2 = {-invdr, -invdr};
    const f32x2 drc2  = {drc, drc};

    const int jbase = jhalf*1024 + w*256;
    for (int j0 = jbase; j0 < jbase + 256; j0 += 32) {
        const int jj = j0 + kgrp*8;
        const float4 a0 = *(const float4*)(xb + 0*NPTS + jj);
        const float4 a1 = *(const float4*)(xb + 0*NPTS + jj + 4);
        const float4 b0 = *(const float4*)(xb + 1*NPTS + jj);
        const float4 b1 = *(const float4*)(xb + 1*NPTS + jj + 4);
        const float4 c0 = *(const float4*)(xb + 2*NPTS + jj);
        const float4 c1 = *(const float4*)(xb + 2*NPTS + jj + 4);
        const f32x2 px[4] = {{a0.x,a0.y},{a0.z,a0.w},{a1.x,a1.y},{a1.z,a1.w}};
        const f32x2 py[4] = {{b0.x,b0.y},{b0.z,b0.w},{b1.x,b1.y},{b1.z,b1.w}};
        const f32x2 pz[4] = {{c0.x,c0.y},{c0.z,c0.w},{c1.x,c1.y},{c1.z,c1.w}};

        U4 pwS[2][3], pwA[2][3];
        #pragma unroll
        for (int it = 0; it < 2; ++it) {
            const float xi = it ? xi1 : xi0;
            const float yi = it ? yi1 : yi0;
            const float zi = it ? zi1 : zi0;
            const f32x2 xi2 = {xi, xi};
            const f32x2 yi2 = {yi, yi};
            const f32x2 zi2 = {zi, zi};
            #pragma unroll
            for (int p = 0; p < 4; ++p) {
                const f32x2 dx = px[p] - xi2;
                const f32x2 dy = py[p] - yi2;
                const f32x2 dz = pz[p] - zi2;
                const f32x2 d2 = dx*dx + dy*dy + dz*dz;
                const f32x2 wdl = d2*mind2 + drc2;
                const float wd0 = __builtin_amdgcn_fmed3f(wdl.x, 0.0f, 1.0f);
                const float wd1 = __builtin_amdgcn_fmed3f(wdl.y, 0.0f, 1.0f);
                if (it) { nrm1 += wd0; nrm1 += wd1; }
                else    { nrm0 += wd0; nrm0 += wd1; }
                const f32x2 inv2 = { wd0 * __builtin_amdgcn_rcpf(fmaxf(d2.x, 1e-12f)),
                                     wd1 * __builtin_amdgcn_rcpf(fmaxf(d2.y, 1e-12f)) };
                #pragma unroll
                for (int ax = 0; ax < 3; ++ax) {
                    const f32x2 da = (ax == 0) ? dx : (ax == 1) ? dy : dz;
                    const f32x2 u = da * inv2;
                    const float s0 = u.x * __builtin_fabsf(da.x);
                    const float s1 = u.y * __builtin_fabsf(da.y);
                    pwS[it][ax].u[p] = cvtpk(s0, s1);
                    pwA[it][ax].u[p] = cvtpk_abs(s0, s1);
                }
            }
        }

        const unsigned short* sb = mb + (size_t)(j0 >> 5) * 12 * 512 + lane*8;
        #pragma unroll
        for (int ax = 0; ax < 3; ++ax) {
            #pragma unroll
            for (int h = 0; h < 2; ++h) {
                const bf16x8 Bd = *(const bf16x8*)(sb + (size_t)((2*ax  )*2 + h)*512);
                const bf16x8 Bs = *(const bf16x8*)(sb + (size_t)((2*ax+1)*2 + h)*512);
                acc[0][h] = __builtin_amdgcn_mfma_f32_16x16x32_bf16(pwS[0][ax].v, Bd, acc[0][h], 0,0,0);
                acc[0][h] = __builtin_amdgcn_mfma_f32_16x16x32_bf16(pwA[0][ax].v, Bs, acc[0][h], 0,0,0);
                acc[1][h] = __builtin_amdgcn_mfma_f32_16x16x32_bf16(pwS[1][ax].v, Bd, acc[1][h], 0,0,0);
                acc[1][h] = __builtin_amdgcn_mfma_f32_16x16x32_bf16(pwA[1][ax].v, Bs, acc[1][h], 0,0,0);
            }
        }
    }

    nrm0 += __shfl_xor(nrm0, 16);  nrm0 += __shfl_xor(nrm0, 32);
    nrm1 += __shfl_xor(nrm1, 16);  nrm1 += __shfl_xor(nrm1, 32);

    #pragma unroll
    for (int it = 0; it < 2; ++it)
        #pragma unroll
        for (int r = 0; r < 4; ++r) {
            lacc[w][it*16 + kgrp*4 + r][iloc]      = acc[it][0][r];
            lacc[w][it*16 + kgrp*4 + r][16 + iloc] = acc[it][1][r];
        }
    if (lane < 16) { lnorm[w][lane] = nrm0; lnorm[w][16 + lane] = nrm1; }
    __syncthreads();

    float* agh = agp + (size_t)jhalf * MROWS * 32;
    #pragma unroll
    for (int rep = 0; rep < 4; ++rep) {
        const int idx = t + rep*256;
        const int i = idx >> 5, c = idx & 31;
        const float s = lacc[0][i][c] + lacc[1][i][c] + lacc[2][i][c] + lacc[3][i][c];
        agh[((size_t)b*NPTS + i0 + i)*32 + c] = s;
    }
    if (t < 32) {
        const float n = lnorm[0][t] + lnorm[1][t] + lnorm[2][t] + lnorm[3][t];
        nrmp[(size_t)jhalf*MROWS + b*NPTS + i0 + t] = n;
    }
}

// ---------------------------------------------------------------------------
// Merge j-half partials, normalize (minus self-pair), write ag, s32 stats.
// ---------------------------------------------------------------------------
__global__ __launch_bounds__(256) void finalize_k(
    const float* __restrict__ agp, const float* __restrict__ nrmp,
    float* __restrict__ ag, float* __restrict__ s32s, float* __restrict__ s32q)
{
    __shared__ float lv[64][33];
    const int t  = threadIdx.x;
    const int r0 = blockIdx.x * 64;

    #pragma unroll
    for (int rep = 0; rep < 2; ++rep) {
        const int lidx = t + rep*256;
        const int rl = lidx >> 3;
        const int c0 = (lidx & 7) * 4;
        const size_t r = (size_t)r0 + rl;
        const float4 p0 = *(const float4*)(agp + r*32 + c0);
        const float4 p1 = *(const float4*)(agp + ((size_t)MROWS + r)*32 + c0);
        const float n = nrmp[r] + nrmp[MROWS + r] - 1.0f;
        const float invn = __builtin_amdgcn_rcpf(fmaxf(n, 1e-12f));
        float4 v;
        v.x = (p0.x + p1.x) * invn;  v.y = (p0.y + p1.y) * invn;
        v.z = (p0.z + p1.z) * invn;  v.w = (p0.w + p1.w) * invn;
        *(float4*)(ag + r*32 + c0) = v;
        lv[rl][c0] = v.x; lv[rl][c0+1] = v.y; lv[rl][c0+2] = v.z; lv[rl][c0+3] = v.w;
    }
    __syncthreads();
    if (t < 32) {
        float ps = 0.0f, pq = 0.0f;
        #pragma unroll
        for (int i = 0; i < 64; ++i) {
            const float v = lv[i][t];
            ps += v; pq = fmaf(v, v, pq);
        }
        atomicAdd(s32s + t, ps);
        atomicAdd(s32q + t, pq);
    }
}

// ---------------------------------------------------------------------------
// lin2f v3 (MFMA, epilogue atomics) — r14-validated.
// ---------------------------------------------------------------------------
__global__ __launch_bounds__(256) void lin2f_mfma_k(
    const float* __restrict__ ag,
    const float* __restrict__ s32s, const float* __restrict__ s32q,
    const float* __restrict__ g1,   const float* __restrict__ be1,
    const unsigned short* __restrict__ Wpk2,
    const float* __restrict__ bag,  const float* __restrict__ selfF,
    float* __restrict__ pre2,
    float* __restrict__ s64s, float* __restrict__ s64q)
{
    __shared__ float sc_[32], sh_[32];
    __shared__ float lps[4][4][16];
    __shared__ float lpq[4][4][16];
    const int t    = threadIdx.x;
    const int lane = t & 63;
    const int w    = t >> 6;
    const int r0   = blockIdx.x * 64 + w * 16;
    const int mrow = lane & 15;
    const int kgrp = lane >> 4;

    if (t < 32) {
        const float invM = 1.0f / (float)MROWS;
        const float mu  = s32s[t] * invM;
        const float var = s32q[t] * invM - mu*mu;
        const float sc  = g1[t] * rsqrtf(var + BN_EPS);
        sc_[t] = sc; sh_[t] = be1[t] - mu * sc;
    }
    __syncthreads();

    U4 Afr;
    {
        const float* src = ag + (size_t)(r0 + mrow)*32 + kgrp*8;
        const float4 v0 = *(const float4*)src;
        const float4 v1 = *(const float4*)(src + 4);
        const int c0 = kgrp*8;
        const float vv[8] = {v0.x,v0.y,v0.z,v0.w,v1.x,v1.y,v1.z,v1.w};
        float bn[8];
        #pragma unroll
        for (int e = 0; e < 8; ++e)
            bn[e] = fmaxf(fmaf(vv[e], sc_[c0+e], sh_[c0+e]), 0.0f);
        Afr.u[0] = cvtpk(bn[0], bn[1]);
        Afr.u[1] = cvtpk(bn[2], bn[3]);
        Afr.u[2] = cvtpk(bn[4], bn[5]);
        Afr.u[3] = cvtpk(bn[6], bn[7]);
    }

    #pragma unroll
    for (int nt = 0; nt < 4; ++nt) {
        const bf16x8 B = *(const bf16x8*)(Wpk2 + (size_t)nt*512 + lane*8);
        f32x4 acc = {0.f,0.f,0.f,0.f};
        acc = __builtin_amdgcn_mfma_f32_16x16x32_bf16(Afr.v, B, acc, 0,0,0);

        const int ncol = nt*16 + mrow;
        const float bias = bag[ncol];
        float s = 0.f, q = 0.f;
        #pragma unroll
        for (int r = 0; r < 4; ++r) {
            const int row = r0 + kgrp*4 + r;
            const float val = acc[r] + bias + selfF[(size_t)row*64 + ncol];
            pre2[(size_t)row*64 + ncol] = val;
            s += val; q = fmaf(val, val, q);
        }
        s += __shfl_xor(s, 16);  s += __shfl_xor(s, 32);
        q += __shfl_xor(q, 16);  q += __shfl_xor(q, 32);
        if (lane < 16) { lps[w][nt][lane] = s; lpq[w][nt][lane] = q; }
    }
    __syncthreads();
    if (t < 64) {
        const int nt = t >> 4, la = t & 15;
        const float s = lps[0][nt][la] + lps[1][nt][la] + lps[2][nt][la] + lps[3][nt][la];
        const float q = lpq[0][nt][la] + lpq[1][nt][la] + lpq[2][nt][la] + lpq[3][nt][la];
        atomicAdd(s64s + t, s);
        atomicAdd(s64q + t, q);
    }
}

// ---------------------------------------------------------------------------
// Final BN+relu (C=64) -> d_out
// ---------------------------------------------------------------------------
template<int C>
__global__ __launch_bounds__(256) void bn_relu_k(
    const float* __restrict__ sum, const float* __restrict__ sq,
    const float* __restrict__ g,   const float* __restrict__ be,
    const float* __restrict__ X, float* __restrict__ Y, int n4)
{
    __shared__ __align__(16) float ssc[C];
    __shared__ __align__(16) float ssh[C];
    const int t = threadIdx.x;
    if (t < C) {
        const float invM = 1.0f / (float)MROWS;
        const float mu  = sum[t] * invM;
        const float var = sq[t] * invM - mu*mu;
        const float sc  = g[t] * rsqrtf(var + BN_EPS);
        ssc[t] = sc;
        ssh[t] = be[t] - mu * sc;
    }
    __syncthreads();
    const float4* __restrict__ X4 = (const float4*)X;
    float4* __restrict__ Y4 = (float4*)Y;
    const int stride = gridDim.x * 256;
    for (int i = blockIdx.x*256 + t; i < n4; i += stride) {
        const int c4 = i % (C/4);
        float4 v = X4[i];
        const float4 sc = ((const float4*)ssc)[c4];
        const float4 sh = ((const float4*)ssh)[c4];
        v.x = fmaxf(fmaf(v.x, sc.x, sh.x), 0.0f);
        v.y = fmaxf(fmaf(v.y, sc.y, sh.y), 0.0f);
        v.z = fmaxf(fmaf(v.z, sc.z, sh.z), 0.0f);
        v.w = fmaxf(fmaf(v.w, sc.w, sh.w), 0.0f);
        Y4[i] = v;
    }
}

// ---------------------------------------------------------------------------
extern "C" void kernel_launch(void* const* d_in, const int* in_sizes, int n_in,
                              void* d_out, int out_size, void* d_ws, size_t ws_size,
                              hipStream_t stream)
{
    const float* feat = (const float*)d_in[0];
    const float* xyz  = (const float*)d_in[1];
    const float* Wf   = (const float*)d_in[2];
    const float* bf   = (const float*)d_in[3];
    const float* Wb   = (const float*)d_in[4];
    const float* gby  = (const float*)d_in[5];
    const float* beby = (const float*)d_in[6];
    const float* g1   = (const float*)d_in[7];
    const float* be1  = (const float*)d_in[8];
    const float* Wag  = (const float*)d_in[9];
    const float* bag  = (const float*)d_in[10];
    const float* g2   = (const float*)d_in[11];
    const float* be2  = (const float*)d_in[12];

    float* ws = (float*)d_ws;
    float* stats = ws;                                  // 1024 f
    float* A   = ws + 1024;                             // self_feat [32768][64]
    float* B   = A + (size_t)MROWS*64;                  // preB; later agp/nrmp; later pre2
    float* C   = B + (size_t)MROWS*192;                 // ag [32768][32]
    float* xT  = C + (size_t)MROWS*32;                  // [16][3][2048]
    unsigned short* mTf  = (unsigned short*)(xT + (size_t)NB*3*NPTS);
    unsigned short* Wpk  = mTf + (size_t)NB*64*12*512;  // 16384 shorts
    unsigned short* Wpk2 = Wpk + 16384;                 // 2048 shorts
    float* agp  = B;                                    // [2][MROWS][32]
    float* nrmp = B + (size_t)MROWS*64;                 // [2][MROWS]
    float* D = B;                                       // pre2 reuses B

    float* s192s = stats;       float* s192q = stats + 192;
    float* s32s  = stats + 384; float* s32q  = stats + 416;
    float* s64s  = stats + 448; float* s64q  = stats + 512;

    (void)hipMemsetAsync(stats, 0, 1024 * sizeof(float), stream);

    prep_k<<<137, 256, 0, stream>>>(Wf, Wb, Wag, xyz, Wpk, Wpk2, xT);
    linear1_mfma_k<<<512, 256, 0, stream>>>(feat, Wpk, bf, A, B, s192s, s192q);

    bn_t192_k<<<1536, 256, 0, stream>>>(s192s, s192q, gby, beby, B, mTf);

    aggregate_mfma_k<<<2048, 256, 0, stream>>>(mTf, xT, agp, nrmp);

    finalize_k<<<512, 256, 0, stream>>>(agp, nrmp, C, s32s, s32q);

    lin2f_mfma_k<<<512, 256, 0, stream>>>(C, s32s, s32q, g1, be1, Wpk2, bag, A, D, s64s, s64q);

    bn_relu_k<64><<<512, 256, 0, stream>>>(s64s, s64q, g2, be2, D, (float*)d_out, MROWS*64/4);
}